// Round 5
// baseline (345.757 us; speedup 1.0000x reference)
//
#include <hip/hip_runtime.h>
#include <hip/hip_bf16.h>

typedef __bf16 bf16x8 __attribute__((ext_vector_type(8)));
typedef float  f32x4  __attribute__((ext_vector_type(4)));

#define B_ROWS 65536
#define MR 32            // rows (images) per block; LDS 62.5KB -> 2 blocks/CU
#define NT_THREADS 512   // 8 waves/block; 2 blocks/CU -> 16 waves/CU (~50% occ)
#define H0S 712          // h0 LDS stride in bf16 (704 used + 8 pad: 1424B -> bank start 4*r)
#define H1S 264          // h1 stride (256 + 8 pad: 528B -> bank start 4*r)
#define H2S 136          // h2 stride (128 + 8 pad: 272B -> bank start 4*r)
#define KC1 22           // 704/32
#define KC2 8            // 256/32
#define KC3 4            // 128/32

#define W1B_ELEMS (704*256)
#define W2B_ELEMS (256*128)
#define W3B_ELEMS (128*16)

// Pack weights to bf16 in MFMA-B layout [kc][n][ki(32)] so a lane's 8 k-values
// (ki = (lane>>4)*8 + j) are 16B-contiguous; whole wave covers 1KB contiguous.
__global__ void pack_weights(const float* __restrict__ w1,
                             const float* __restrict__ w2,
                             const float* __restrict__ w3,
                             __hip_bfloat16* __restrict__ w1b,
                             __hip_bfloat16* __restrict__ w2b,
                             __hip_bfloat16* __restrict__ w3b) {
    int idx = blockIdx.x * 256 + threadIdx.x;
    if (idx < W1B_ELEMS) {
        int ki = idx & 31, t = idx >> 5;
        int n = t & 255, kc = t >> 8;
        int k = kc * 32 + ki;
        float v = (k < 676) ? w1[k * 256 + n] : 0.0f;   // zero-pad K 676->704
        w1b[idx] = __float2bfloat16(v);
    } else if (idx < W1B_ELEMS + W2B_ELEMS) {
        int j = idx - W1B_ELEMS;
        int ki = j & 31, t = j >> 5;
        int n = t & 127, kc = t >> 7;
        w2b[j] = __float2bfloat16(w2[(kc * 32 + ki) * 128 + n]);
    } else if (idx < W1B_ELEMS + W2B_ELEMS + W3B_ELEMS) {
        int j = idx - W1B_ELEMS - W2B_ELEMS;
        int ki = j & 31, t = j >> 5;
        int n = t & 15, kc = t >> 4;
        float v = (n < 10) ? w3[(kc * 32 + ki) * 10 + n] : 0.0f;  // zero-pad N 10->16
        w3b[j] = __float2bfloat16(v);
    }
}

// Fused conv3x3(valid) + 676->256 relu + 256->128 relu + 128->10.
// 32 rows per block, 512 threads (8 waves). LDS 62.5KB -> 2 blocks/CU
// -> 16 waves/CU (~50% occ) at VGPR<=128. Latency-bound kernel: this round
// buys TLP while the asm pins preserve MLP (round-1 lesson).
__global__ __launch_bounds__(NT_THREADS, 4)
void fused_model(const float* __restrict__ x, const float* __restrict__ cw,
                 const __hip_bfloat16* __restrict__ w1b, const float* __restrict__ b1,
                 const __hip_bfloat16* __restrict__ w2b, const float* __restrict__ b2,
                 const __hip_bfloat16* __restrict__ w3b, const float* __restrict__ b3,
                 float* __restrict__ out) {
    // LDS: [h0: 32*712*2 = 45568][h1: 32*264*2 = 16896] = 62464B. h2 overlays dead h0.
    __shared__ __align__(16) char smem[MR * H0S * 2 + MR * H1S * 2];
    __hip_bfloat16* h0s = (__hip_bfloat16*)smem;
    __hip_bfloat16* h1s = (__hip_bfloat16*)(smem + MR * H0S * 2);
    __hip_bfloat16* h2s = (__hip_bfloat16*)smem;

    const int tid = threadIdx.x;
    const int r0  = blockIdx.x * MR;

    const float c00 = cw[0], c01 = cw[1], c02 = cw[2];
    const float c10 = cw[3], c11 = cw[4], c12 = cw[5];
    const float c20 = cw[6], c21 = cw[7], c22 = cw[8];

    // ---- Stage 1: conv (fp32 exact), h0[r][i*26+j] -> LDS bf16 ----
    // One task = one (image r, output row i). ALL 21 float4 loads issued and
    // PINNED via empty asm on their scalar components (compiler may not sink
    // them): one HBM latency wait per task with 21 loads in flight, not 3x7.
    // 832 tasks / 512 threads = 2 barrier-rounds (was 4 with 256 threads).
    for (int t = tid; t < MR * 26; t += NT_THREADS) {
        int r = t / 26;
        int i = t - r * 26;
        const float* xr = x + (size_t)(r0 + r) * 784 + i * 28;
        float4 v[21];
        #pragma unroll
        for (int di = 0; di < 3; di++) {
            const float4* p4 = (const float4*)(xr + di * 28);  // 16B aligned
            #pragma unroll
            for (int q = 0; q < 7; q++) v[di * 7 + q] = p4[q];
        }
        #pragma unroll
        for (int k = 0; k < 21; k++)
            asm volatile("" :: "v"(v[k].x), "v"(v[k].y), "v"(v[k].z), "v"(v[k].w));
        float rb[3][28];
        #pragma unroll
        for (int di = 0; di < 3; di++) {
            #pragma unroll
            for (int q = 0; q < 7; q++) {
                rb[di][q*4+0] = v[di*7+q].x; rb[di][q*4+1] = v[di*7+q].y;
                rb[di][q*4+2] = v[di*7+q].z; rb[di][q*4+3] = v[di*7+q].w;
            }
        }
        __hip_bfloat162* hp = (__hip_bfloat162*)(h0s + r * H0S + i * 26);  // i*52B, 4B aligned
        #pragma unroll
        for (int k = 0; k < 13; k++) {
            const int j0 = 2 * k, j1 = 2 * k + 1;
            float a0 = c00*rb[0][j0] + c01*rb[0][j0+1] + c02*rb[0][j0+2]
                     + c10*rb[1][j0] + c11*rb[1][j0+1] + c12*rb[1][j0+2]
                     + c20*rb[2][j0] + c21*rb[2][j0+1] + c22*rb[2][j0+2];
            float a1 = c00*rb[0][j1] + c01*rb[0][j1+1] + c02*rb[0][j1+2]
                     + c10*rb[1][j1] + c11*rb[1][j1+1] + c12*rb[1][j1+2]
                     + c20*rb[2][j1] + c21*rb[2][j1+1] + c22*rb[2][j1+2];
            __hip_bfloat162 pr;
            pr.x = __float2bfloat16(a0);
            pr.y = __float2bfloat16(a1);
            hp[k] = pr;
        }
    }
    // zero K-pad cols 676..711 as dwords (avoid NaN garbage under padded-K MFMA)
    for (int t = tid; t < MR * 18; t += NT_THREADS) {
        int r = t / 18;
        int c = t - r * 18;
        ((uint*)(h0s + r * H0S + 676))[c] = 0u;   // 676*2=1352B, 4B aligned
    }
    __syncthreads();

    const int wave = tid >> 6;
    const int lane = tid & 63;
    const int l15  = lane & 15;
    const int g    = lane >> 4;

    // ---- Stage 2: GEMM1  h1 = relu(h0 @ w1 + b1), M=32 N=256 K=704 ----
    // 8 waves x N=32 slice. 3-slot register pipeline, prefetch distance 2:
    // w1b L2 latency covered by MFMA + 4-wave/SIMD interleave.
    {
        f32x4 acc[2][2];
        #pragma unroll
        for (int mt = 0; mt < 2; mt++)
            #pragma unroll
            for (int nt = 0; nt < 2; nt++)
                acc[mt][nt] = (f32x4){0.f, 0.f, 0.f, 0.f};
        const int nb = wave * 32;
        bf16x8 ab[3][2], bb[3][2];
        #pragma unroll
        for (int p = 0; p < 2; p++) {
            #pragma unroll
            for (int mt = 0; mt < 2; mt++)
                ab[p][mt] = *(const bf16x8*)(h0s + (mt * 16 + l15) * H0S + p * 32 + g * 8);
            #pragma unroll
            for (int nt = 0; nt < 2; nt++)
                bb[p][nt] = *(const bf16x8*)(w1b + ((p * 256 + nb + nt * 16 + l15) * 32 + g * 8));
        }
        #pragma unroll
        for (int kc = 0; kc < KC1; kc++) {
            const int cur = kc % 3;
            const int nxt = (kc + 2) % 3;
            if (kc + 2 < KC1) {
                #pragma unroll
                for (int mt = 0; mt < 2; mt++)
                    ab[nxt][mt] = *(const bf16x8*)(h0s + (mt * 16 + l15) * H0S + (kc + 2) * 32 + g * 8);
                #pragma unroll
                for (int nt = 0; nt < 2; nt++)
                    bb[nxt][nt] = *(const bf16x8*)(w1b + (((kc + 2) * 256 + nb + nt * 16 + l15) * 32 + g * 8));
            }
            #pragma unroll
            for (int mt = 0; mt < 2; mt++)
                #pragma unroll
                for (int nt = 0; nt < 2; nt++)
                    acc[mt][nt] = __builtin_amdgcn_mfma_f32_16x16x32_bf16(
                        ab[cur][mt], bb[cur][nt], acc[mt][nt], 0, 0, 0);
        }
        #pragma unroll
        for (int nt = 0; nt < 2; nt++) {
            const int n = nb + nt * 16 + l15;
            const float bias = b1[n];
            #pragma unroll
            for (int mt = 0; mt < 2; mt++) {
                #pragma unroll
                for (int q = 0; q < 4; q++) {
                    const int row = mt * 16 + g * 4 + q;   // C/D: col=lane&15, row=(lane>>4)*4+q
                    float v = acc[mt][nt][q] + bias;
                    h1s[row * H1S + n] = __float2bfloat16(fmaxf(v, 0.0f));
                }
            }
        }
    }
    __syncthreads();

    // ---- Stage 3: GEMM2  h2 = relu(h1 @ w2 + b2), M=32 N=128 K=256 ----
    // 8 waves x N=16 slice.
    {
        f32x4 acc[2];
        #pragma unroll
        for (int mt = 0; mt < 2; mt++)
            acc[mt] = (f32x4){0.f, 0.f, 0.f, 0.f};
        const int nb = wave * 16;
        bf16x8 ab[3][2], bb[3];
        #pragma unroll
        for (int p = 0; p < 2; p++) {
            #pragma unroll
            for (int mt = 0; mt < 2; mt++)
                ab[p][mt] = *(const bf16x8*)(h1s + (mt * 16 + l15) * H1S + p * 32 + g * 8);
            bb[p] = *(const bf16x8*)(w2b + ((p * 128 + nb + l15) * 32 + g * 8));
        }
        #pragma unroll
        for (int kc = 0; kc < KC2; kc++) {
            const int cur = kc % 3;
            const int nxt = (kc + 2) % 3;
            if (kc + 2 < KC2) {
                #pragma unroll
                for (int mt = 0; mt < 2; mt++)
                    ab[nxt][mt] = *(const bf16x8*)(h1s + (mt * 16 + l15) * H1S + (kc + 2) * 32 + g * 8);
                bb[nxt] = *(const bf16x8*)(w2b + (((kc + 2) * 128 + nb + l15) * 32 + g * 8));
            }
            #pragma unroll
            for (int mt = 0; mt < 2; mt++)
                acc[mt] = __builtin_amdgcn_mfma_f32_16x16x32_bf16(
                    ab[cur][mt], bb[cur], acc[mt], 0, 0, 0);
        }
        {
            const int n = nb + l15;
            const float bias = b2[n];
            #pragma unroll
            for (int mt = 0; mt < 2; mt++) {
                #pragma unroll
                for (int q = 0; q < 4; q++) {
                    const int row = mt * 16 + g * 4 + q;
                    float v = acc[mt][q] + bias;
                    h2s[row * H2S + n] = __float2bfloat16(fmaxf(v, 0.0f));  // h2 overlays h0 (dead)
                }
            }
        }
    }
    __syncthreads();

    // ---- Stage 4: GEMM3  out = h2 @ w3 + b3, M=32 N=16(10) K=128 ----
    if (wave < 2) {
        f32x4 acc3 = (f32x4){0.f, 0.f, 0.f, 0.f};
        #pragma unroll
        for (int kc = 0; kc < KC3; kc++) {
            bf16x8 a = *(const bf16x8*)(h2s + (wave * 16 + l15) * H2S + kc * 32 + g * 8);
            bf16x8 b = *(const bf16x8*)(w3b + ((kc * 16 + l15) * 32 + g * 8));
            acc3 = __builtin_amdgcn_mfma_f32_16x16x32_bf16(a, b, acc3, 0, 0, 0);
        }
        if (l15 < 10) {
            const float bias = b3[l15];
            #pragma unroll
            for (int q = 0; q < 4; q++) {
                const int row = wave * 16 + g * 4 + q;
                out[(size_t)(r0 + row) * 10 + l15] = acc3[q] + bias;
            }
        }
    }
}

extern "C" void kernel_launch(void* const* d_in, const int* in_sizes, int n_in,
                              void* d_out, int out_size, void* d_ws, size_t ws_size,
                              hipStream_t stream) {
    const float* x  = (const float*)d_in[0];
    const float* cw = (const float*)d_in[1];
    const float* w1 = (const float*)d_in[2];
    const float* b1 = (const float*)d_in[3];
    const float* w2 = (const float*)d_in[4];
    const float* b2 = (const float*)d_in[5];
    const float* w3 = (const float*)d_in[6];
    const float* b3 = (const float*)d_in[7];
    float* out = (float*)d_out;

    __hip_bfloat16* w1b = (__hip_bfloat16*)d_ws;
    __hip_bfloat16* w2b = w1b + W1B_ELEMS;
    __hip_bfloat16* w3b = w2b + W2B_ELEMS;

    const int pack_total = W1B_ELEMS + W2B_ELEMS + W3B_ELEMS;  // 215040
    pack_weights<<<(pack_total + 255) / 256, 256, 0, stream>>>(w1, w2, w3, w1b, w2b, w3b);
    fused_model<<<B_ROWS / MR, NT_THREADS, 0, stream>>>(x, cw, w1b, b1, w2b, b2, w3b, b3, out);
}

// Round 6
// 333.316 us; speedup vs baseline: 1.0373x; 1.0373x over previous
//
#include <hip/hip_runtime.h>
#include <hip/hip_bf16.h>

typedef __bf16 bf16x8 __attribute__((ext_vector_type(8)));
typedef float  f32x4  __attribute__((ext_vector_type(4)));

#define B_ROWS 65536
#define MR 32            // rows (images) per block; LDS 62.5KB -> 2 blocks/CU
#define H0S 712          // h0 LDS stride in bf16 (704 used + 8 pad: 1424B -> bank start 4*r)
#define H1S 264          // h1 stride (256 + 8 pad: 528B -> bank start 4*r)
#define H2S 136          // h2 stride (128 + 8 pad: 272B -> bank start 4*r)
#define KC1 22           // 704/32
#define KC2 8            // 256/32
#define KC3 4            // 128/32
#define STW 29           // x-stage row stride in floats (28+1: conflict-free reads)
#define STG_FLOATS (28*STW)   // 812 floats = 3248B per wave

#define W1B_ELEMS (704*256)
#define W2B_ELEMS (256*128)
#define W3B_ELEMS (128*16)

// Pack weights to bf16 in MFMA-B layout [kc][n][ki(32)] so a lane's 8 k-values
// (ki = (lane>>4)*8 + j) are 16B-contiguous; whole wave covers 1KB contiguous.
__global__ void pack_weights(const float* __restrict__ w1,
                             const float* __restrict__ w2,
                             const float* __restrict__ w3,
                             __hip_bfloat16* __restrict__ w1b,
                             __hip_bfloat16* __restrict__ w2b,
                             __hip_bfloat16* __restrict__ w3b) {
    int idx = blockIdx.x * 256 + threadIdx.x;
    if (idx < W1B_ELEMS) {
        int ki = idx & 31, t = idx >> 5;
        int n = t & 255, kc = t >> 8;
        int k = kc * 32 + ki;
        float v = (k < 676) ? w1[k * 256 + n] : 0.0f;   // zero-pad K 676->704
        w1b[idx] = __float2bfloat16(v);
    } else if (idx < W1B_ELEMS + W2B_ELEMS) {
        int j = idx - W1B_ELEMS;
        int ki = j & 31, t = j >> 5;
        int n = t & 127, kc = t >> 7;
        w2b[j] = __float2bfloat16(w2[(kc * 32 + ki) * 128 + n]);
    } else if (idx < W1B_ELEMS + W2B_ELEMS + W3B_ELEMS) {
        int j = idx - W1B_ELEMS - W2B_ELEMS;
        int ki = j & 31, t = j >> 5;
        int n = t & 15, kc = t >> 4;
        float v = (n < 10) ? w3[(kc * 32 + ki) * 10 + n] : 0.0f;  // zero-pad N 10->16
        w3b[j] = __float2bfloat16(v);
    }
}

// Fused conv3x3(valid) + 676->256 relu + 256->128 relu + 128->10.
// 32 rows per block, 256 threads (4 waves). LDS 62.5KB -> 2 blocks/CU.
// Conv restructured (R6): wave-per-image streaming. Each wave reads its image
// CONTIGUOUSLY (4 coalesced 1KB wave-loads), stages to private LDS buffer,
// computes conv from LDS while the NEXT image's loads are in flight (T14).
// This replaces the fragile per-lane scattered-load conv that capped HBM ~800GB/s.
__global__ __launch_bounds__(256, 2)
void fused_model(const float* __restrict__ x, const float* __restrict__ cw,
                 const __hip_bfloat16* __restrict__ w1b, const float* __restrict__ b1,
                 const __hip_bfloat16* __restrict__ w2b, const float* __restrict__ b2,
                 const __hip_bfloat16* __restrict__ w3b, const float* __restrict__ b3,
                 float* __restrict__ out) {
    // LDS: [h0: 32*712*2 = 45568][h1: 32*264*2 = 16896] = 62464B.
    // x-stage (4 waves * 3248B = 12992B) overlays h1 (dead during conv).
    // h2 overlays h0 (dead after GEMM2 reads it... h0 dead after GEMM1).
    __shared__ __align__(16) char smem[MR * H0S * 2 + MR * H1S * 2];
    __hip_bfloat16* h0s = (__hip_bfloat16*)smem;
    __hip_bfloat16* h1s = (__hip_bfloat16*)(smem + MR * H0S * 2);
    __hip_bfloat16* h2s = (__hip_bfloat16*)smem;

    const int tid  = threadIdx.x;
    const int r0   = blockIdx.x * MR;
    const int wave = tid >> 6;
    const int lane = tid & 63;

    const float c00 = cw[0], c01 = cw[1], c02 = cw[2];
    const float c10 = cw[3], c11 = cw[4], c12 = cw[5];
    const float c20 = cw[6], c21 = cw[7], c22 = cw[8];

    // ---- Stage 1: conv (fp32 exact), h0[r][i*26+j] -> LDS bf16 ----
    // Wave w handles images r = w*8 + gi, gi=0..7. Per image: 196 float4 read
    // contiguously (lane-strided: 4 wave-loads of 1KB), staged to stg[28][29]
    // f32 (stride 29 -> rows hit distinct banks). Compute: lane l<52 owns
    // (row i=l>>1, col-half half=l&1): 3x15 window -> 13 outputs.
    {
        float* stg = ((float*)(smem + MR * H0S * 2)) + wave * STG_FLOATS;
        float4 rg[4];
        {   // prologue: load image gi=0
            const float4* xb = (const float4*)(x + (size_t)(r0 + wave * 8) * 784);
            #pragma unroll
            for (int q = 0; q < 4; q++) {
                int fidx = q * 64 + lane;
                rg[q] = xb[fidx < 196 ? fidx : 195];   // clamp, no branch
            }
        }
        for (int gi = 0; gi < 8; gi++) {
            // write staged registers -> LDS (scalar b32: stride-29 rows are not
            // 16B aligned; compiler may fuse to b64 where possible)
            #pragma unroll
            for (int q = 0; q < 4; q++) {
                int fidx = q * 64 + lane;
                if (fidx < 196) {
                    int row = fidx / 7, c4 = (fidx - row * 7) * 4;
                    float* p = stg + row * STW + c4;
                    p[0] = rg[q].x; p[1] = rg[q].y; p[2] = rg[q].z; p[3] = rg[q].w;
                }
            }
            // issue next image's global loads NOW (hide HBM under compute)
            if (gi < 7) {
                const float4* xb = (const float4*)(x + (size_t)(r0 + wave * 8 + gi + 1) * 784);
                #pragma unroll
                for (int q = 0; q < 4; q++) {
                    int fidx = q * 64 + lane;
                    rg[q] = xb[fidx < 196 ? fidx : 195];
                }
            }
            // compute conv for image gi from LDS window
            if (lane < 52) {
                const int i  = lane >> 1;
                const int c0 = (lane & 1) * 13;
                const float* s0 = stg + i * STW + c0;
                float w0[15], w1r[15], w2r[15];
                #pragma unroll
                for (int c = 0; c < 15; c++) {
                    w0[c]  = s0[c];
                    w1r[c] = s0[STW + c];
                    w2r[c] = s0[2 * STW + c];
                }
                const int r = wave * 8 + gi;
                __hip_bfloat16* hp = h0s + r * H0S + i * 26 + c0;
                #pragma unroll
                for (int jj = 0; jj < 13; jj++) {
                    float a = c00 * w0[jj]  + c01 * w0[jj + 1]  + c02 * w0[jj + 2]
                            + c10 * w1r[jj] + c11 * w1r[jj + 1] + c12 * w1r[jj + 2]
                            + c20 * w2r[jj] + c21 * w2r[jj + 1] + c22 * w2r[jj + 2];
                    hp[jj] = __float2bfloat16(a);
                }
            }
        }
    }
    // zero K-pad cols 676..711 as dwords (avoid NaN garbage under padded-K MFMA)
    for (int t = tid; t < MR * 18; t += 256) {
        int r = t / 18;
        int c = t - r * 18;
        ((uint*)(h0s + r * H0S + 676))[c] = 0u;   // 676*2=1352B, 4B aligned
    }
    __syncthreads();

    const int l15 = lane & 15;
    const int g   = lane >> 4;

    // ---- Stage 2: GEMM1  h1 = relu(h0 @ w1 + b1), M=32 N=256 K=704 ----
    // 3-slot register pipeline, prefetch distance 2: w1b L2 latency (~200cy)
    // covered by ~2x8 MFMA + wave interleave. Fully unrolled -> static indices.
    {
        f32x4 acc[2][4];
        #pragma unroll
        for (int mt = 0; mt < 2; mt++)
            #pragma unroll
            for (int nt = 0; nt < 4; nt++)
                acc[mt][nt] = (f32x4){0.f, 0.f, 0.f, 0.f};
        const int nb = wave * 64;
        bf16x8 ab[3][2], bb[3][4];
        #pragma unroll
        for (int p = 0; p < 2; p++) {
            #pragma unroll
            for (int mt = 0; mt < 2; mt++)
                ab[p][mt] = *(const bf16x8*)(h0s + (mt * 16 + l15) * H0S + p * 32 + g * 8);
            #pragma unroll
            for (int nt = 0; nt < 4; nt++)
                bb[p][nt] = *(const bf16x8*)(w1b + ((p * 256 + nb + nt * 16 + l15) * 32 + g * 8));
        }
        #pragma unroll
        for (int kc = 0; kc < KC1; kc++) {
            const int cur = kc % 3;
            const int nxt = (kc + 2) % 3;
            if (kc + 2 < KC1) {
                #pragma unroll
                for (int mt = 0; mt < 2; mt++)
                    ab[nxt][mt] = *(const bf16x8*)(h0s + (mt * 16 + l15) * H0S + (kc + 2) * 32 + g * 8);
                #pragma unroll
                for (int nt = 0; nt < 4; nt++)
                    bb[nxt][nt] = *(const bf16x8*)(w1b + (((kc + 2) * 256 + nb + nt * 16 + l15) * 32 + g * 8));
            }
            #pragma unroll
            for (int mt = 0; mt < 2; mt++)
                #pragma unroll
                for (int nt = 0; nt < 4; nt++)
                    acc[mt][nt] = __builtin_amdgcn_mfma_f32_16x16x32_bf16(
                        ab[cur][mt], bb[cur][nt], acc[mt][nt], 0, 0, 0);
        }
        #pragma unroll
        for (int nt = 0; nt < 4; nt++) {
            const int n = nb + nt * 16 + l15;
            const float bias = b1[n];
            #pragma unroll
            for (int mt = 0; mt < 2; mt++) {
                #pragma unroll
                for (int q = 0; q < 4; q++) {
                    const int row = mt * 16 + g * 4 + q;   // C/D: col=lane&15, row=(lane>>4)*4+q
                    float v = acc[mt][nt][q] + bias;
                    h1s[row * H1S + n] = __float2bfloat16(fmaxf(v, 0.0f));
                }
            }
        }
    }
    __syncthreads();

    // ---- Stage 3: GEMM2  h2 = relu(h1 @ w2 + b2), M=32 N=128 K=256 ----
    {
        f32x4 acc[2][2];
        #pragma unroll
        for (int mt = 0; mt < 2; mt++)
            #pragma unroll
            for (int nt = 0; nt < 2; nt++)
                acc[mt][nt] = (f32x4){0.f, 0.f, 0.f, 0.f};
        const int nb = wave * 32;
        bf16x8 ab[3][2], bb[3][2];
        #pragma unroll
        for (int p = 0; p < 2; p++) {
            #pragma unroll
            for (int mt = 0; mt < 2; mt++)
                ab[p][mt] = *(const bf16x8*)(h1s + (mt * 16 + l15) * H1S + p * 32 + g * 8);
            #pragma unroll
            for (int nt = 0; nt < 2; nt++)
                bb[p][nt] = *(const bf16x8*)(w2b + ((p * 128 + nb + nt * 16 + l15) * 32 + g * 8));
        }
        #pragma unroll
        for (int kc = 0; kc < KC2; kc++) {
            const int cur = kc % 3;
            const int nxt = (kc + 2) % 3;
            if (kc + 2 < KC2) {
                #pragma unroll
                for (int mt = 0; mt < 2; mt++)
                    ab[nxt][mt] = *(const bf16x8*)(h1s + (mt * 16 + l15) * H1S + (kc + 2) * 32 + g * 8);
                #pragma unroll
                for (int nt = 0; nt < 2; nt++)
                    bb[nxt][nt] = *(const bf16x8*)(w2b + (((kc + 2) * 128 + nb + nt * 16 + l15) * 32 + g * 8));
            }
            #pragma unroll
            for (int mt = 0; mt < 2; mt++)
                #pragma unroll
                for (int nt = 0; nt < 2; nt++)
                    acc[mt][nt] = __builtin_amdgcn_mfma_f32_16x16x32_bf16(
                        ab[cur][mt], bb[cur][nt], acc[mt][nt], 0, 0, 0);
        }
        #pragma unroll
        for (int nt = 0; nt < 2; nt++) {
            const int n = nb + nt * 16 + l15;
            const float bias = b2[n];
            #pragma unroll
            for (int mt = 0; mt < 2; mt++) {
                #pragma unroll
                for (int q = 0; q < 4; q++) {
                    const int row = mt * 16 + g * 4 + q;
                    float v = acc[mt][nt][q] + bias;
                    h2s[row * H2S + n] = __float2bfloat16(fmaxf(v, 0.0f));  // h2 overlays h0 (dead)
                }
            }
        }
    }
    __syncthreads();

    // ---- Stage 4: GEMM3  out = h2 @ w3 + b3, M=32 N=16(10) K=128 ----
    if (wave < 2) {
        f32x4 acc3 = (f32x4){0.f, 0.f, 0.f, 0.f};
        #pragma unroll
        for (int kc = 0; kc < KC3; kc++) {
            bf16x8 a = *(const bf16x8*)(h2s + (wave * 16 + l15) * H2S + kc * 32 + g * 8);
            bf16x8 b = *(const bf16x8*)(w3b + ((kc * 16 + l15) * 32 + g * 8));
            acc3 = __builtin_amdgcn_mfma_f32_16x16x32_bf16(a, b, acc3, 0, 0, 0);
        }
        if (l15 < 10) {
            const float bias = b3[l15];
            #pragma unroll
            for (int q = 0; q < 4; q++) {
                const int row = wave * 16 + g * 4 + q;
                out[(size_t)(r0 + row) * 10 + l15] = acc3[q] + bias;
            }
        }
    }
}

extern "C" void kernel_launch(void* const* d_in, const int* in_sizes, int n_in,
                              void* d_out, int out_size, void* d_ws, size_t ws_size,
                              hipStream_t stream) {
    const float* x  = (const float*)d_in[0];
    const float* cw = (const float*)d_in[1];
    const float* w1 = (const float*)d_in[2];
    const float* b1 = (const float*)d_in[3];
    const float* w2 = (const float*)d_in[4];
    const float* b2 = (const float*)d_in[5];
    const float* w3 = (const float*)d_in[6];
    const float* b3 = (const float*)d_in[7];
    float* out = (float*)d_out;

    __hip_bfloat16* w1b = (__hip_bfloat16*)d_ws;
    __hip_bfloat16* w2b = w1b + W1B_ELEMS;
    __hip_bfloat16* w3b = w2b + W2B_ELEMS;

    const int pack_total = W1B_ELEMS + W2B_ELEMS + W3B_ELEMS;  // 215040
    pack_weights<<<(pack_total + 255) / 256, 256, 0, stream>>>(w1, w2, w3, w1b, w2b, w3b);
    fused_model<<<B_ROWS / MR, 256, 0, stream>>>(x, cw, w1b, b1, w2b, b2, w3b, b3, out);
}